// Round 13
// baseline (856.569 us; speedup 1.0000x reference)
//
// v21: k_stats REVERTED to v15's byte-proven version (2ch x 512 blocks, measured
// in the 800us best total). v19/v20 deep-pipeline stats abandoned: correctness
// failure not localizable without disasm (suspect: compiler VMEM ops corrupting
// the counted-vmcnt ledger). k_conv: v11's 4 px/thread retried with the root
// cause fixed — launch_bounds(512,1) (v11's (512,2) capped VGPR at 128 = exactly
// the accumulator size -> spilled everything). 128 FMA per 128B weight row.
#include <hip/hip_runtime.h>

#define OFF_PSUM   0UL            // 134217728 B  f32 psum[b][1024][32][32]
#define OFF_ALPHA  134217728UL    // 1024 B
#define OFF_INV    134218752UL    // 4096 B
#define OFF_BT     134222848UL    // 4096 B   (total 134.23 MB, proven fits)

// ---------------- K0a: alpha — LDS-staged, exact sequential chain ----------------
__global__ __launch_bounds__(256) void k_alpha(const float* __restrict__ w,
                                               float* __restrict__ alpha) {
#pragma clang fp contract(off)
    __shared__ float buf[2304];
    int co = blockIdx.x, t = threadIdx.x;
    const float* p = w + (size_t)co * 2304;
    for (int i = t; i < 2304; i += 256) buf[i] = p[i];
    __syncthreads();
    if (t == 0) {
        float s = 0.f;
#pragma unroll 16
        for (int k = 0; k < 2304; ++k) s = s + fabsf(buf[k]);
        alpha[co] = s / 2304.0f;
    }
}

// ---------------- K0b: transposed +-alpha table wsaT[((g*9+tap)*64+ci)*256+co] ----------------
__global__ __launch_bounds__(256) void k_wsaT(const float* __restrict__ w,
                                              const float* __restrict__ alpha,
                                              float* __restrict__ wsaT) {
    int item = blockIdx.x * 256 + threadIdx.x;     // 589824 items
    int co = item & 255;
    int rest = item >> 8;                           // 0..2303
    int ci = rest & 63;
    int t9 = rest >> 6;                             // 0..35
    int tap = t9 % 9, g = t9 / 9;
    float av = alpha[co];
    float wv = w[((size_t)co * 256 + g * 64 + ci) * 9 + tap];
    wsaT[item] = (wv >= 0.f) ? av : -av;           // exact +-alpha
}

// ---------------- K1: conv — 4 px/thread, SGPR weights, 128 FMA per weight row ----------------
// block (b,g,band8): 8 waves x 32 co; thread = px rows h0+{0,2,4,6}, col m.
// launch_bounds(512,1): VGPR cap 256 (v11's (512,2) cap of 128 = acc size -> spill).
__global__ __launch_bounds__(512, 1) void k_conv(const float* __restrict__ x,
                                                 const float* __restrict__ wsaT,
                                                 float* __restrict__ psum) {
#pragma clang fp contract(off)
    __shared__ float xs[10][34][68];               // 92480 B -> 1 block/CU
    int bx = blockIdx.x;
    int band = bx & 3, g = (bx >> 2) & 3, b = bx >> 4;   // 512 blocks
    int t = threadIdx.x;

    const float* xg = x + (size_t)(b * 256 + g * 64) * 1024;
#pragma unroll 1
    for (int i = 0; i < 43; ++i) {                 // 10*34*64 = 21760 elements
        int idx = i * 512 + t;
        if (idx < 21760) {
            int ci = idx & 63, col = (idx >> 6) % 34, row = idx / 2176;
            int gr = band * 8 + row - 1, gc = col - 1;
            float v = (gr >= 0 && gr < 32 && gc >= 0 && gc < 32)
                        ? xg[(size_t)ci * 1024 + gr * 32 + gc] : 0.f;
            xs[row][col][ci] = v;
        }
    }
    __syncthreads();

    int wid = t >> 6, lane = t & 63;
    int r = lane >> 5, m = lane & 31;
    int h0 = band * 8 + r;                          // px rows h0, h0+2, h0+4, h0+6
    int cobase = __builtin_amdgcn_readfirstlane(wid * 32);   // wave-uniform

    float acc0[32], acc1[32], acc2[32], acc3[32];
#pragma unroll
    for (int j = 0; j < 32; ++j) { acc0[j] = 0.f; acc1[j] = 0.f; acc2[j] = 0.f; acc3[j] = 0.f; }

#pragma unroll 1
    for (int kh = 0; kh < 3; ++kh)
#pragma unroll 1
        for (int kw = 0; kw < 3; ++kw) {
            int tap = kh * 3 + kw;
            const float* bp0 = &xs[r + 0 + kh][m + kw][0];
            const float* bp1 = &xs[r + 2 + kh][m + kw][0];
            const float* bp2 = &xs[r + 4 + kh][m + kw][0];
            const float* bp3 = &xs[r + 6 + kh][m + kw][0];
            const float* wt = wsaT + (((size_t)(g * 9 + tap) * 64) << 8) + cobase;
#pragma unroll
            for (int c = 0; c < 4; ++c) {           // ci chunks of 16
                float xv0[16], xv1[16], xv2[16], xv3[16];
#pragma unroll
                for (int q = 0; q < 4; ++q) {
                    float4 a = *(const float4*)(bp0 + c * 16 + q * 4);
                    xv0[q * 4 + 0] = a.x; xv0[q * 4 + 1] = a.y;
                    xv0[q * 4 + 2] = a.z; xv0[q * 4 + 3] = a.w;
                    float4 d = *(const float4*)(bp1 + c * 16 + q * 4);
                    xv1[q * 4 + 0] = d.x; xv1[q * 4 + 1] = d.y;
                    xv1[q * 4 + 2] = d.z; xv1[q * 4 + 3] = d.w;
                    float4 e = *(const float4*)(bp2 + c * 16 + q * 4);
                    xv2[q * 4 + 0] = e.x; xv2[q * 4 + 1] = e.y;
                    xv2[q * 4 + 2] = e.z; xv2[q * 4 + 3] = e.w;
                    float4 f = *(const float4*)(bp3 + c * 16 + q * 4);
                    xv3[q * 4 + 0] = f.x; xv3[q * 4 + 1] = f.y;
                    xv3[q * 4 + 2] = f.z; xv3[q * 4 + 3] = f.w;
                }
#pragma unroll
                for (int ci = 0; ci < 16; ++ci) {   // per-acc chain order preserved
                    const float* wr = wt + ((c * 16 + ci) << 8);  // uniform -> s_load
#pragma unroll
                    for (int j = 0; j < 32; ++j)
                        acc0[j] = fmaf(xv0[ci], wr[j], acc0[j]);
#pragma unroll
                    for (int j = 0; j < 32; ++j)
                        acc1[j] = fmaf(xv1[ci], wr[j], acc1[j]);
#pragma unroll
                    for (int j = 0; j < 32; ++j)
                        acc2[j] = fmaf(xv2[ci], wr[j], acc2[j]);
#pragma unroll
                    for (int j = 0; j < 32; ++j)
                        acc3[j] = fmaf(xv3[ci], wr[j], acc3[j]);
                }
            }
        }

#pragma unroll
    for (int j = 0; j < 32; ++j) {
        int co = cobase + j;
        size_t rowo = ((size_t)b * 1024 + g * 256 + co) * 32;
        psum[(rowo + h0) * 32 + m]     = acc0[j];
        psum[(rowo + h0 + 2) * 32 + m] = acc1[j];
        psum[(rowo + h0 + 4) * 32 + m] = acc2[j];
        psum[(rowo + h0 + 6) * 32 + m] = acc3[j];
    }
}

// ---------------- K2: BN stats — v15 verbatim (proven in the 800us total) ----------------
typedef float f4 __attribute__((ext_vector_type(4)));

__global__ __launch_bounds__(64, 1) void k_stats(const float* __restrict__ psum,
                                                 const float* __restrict__ gamma,
                                                 const float* __restrict__ beta,
                                                 float* __restrict__ invA,
                                                 float* __restrict__ btA) {
#pragma clang fp contract(off)
    __shared__ float ld[4][2][1028];               // 32896 B; 4 bufs x 2 ch, +4 pad
    int blk = blockIdx.x, lane = threadIdx.x;
    int chb = blk * 2;

    unsigned lbase;
    {
        __attribute__((address_space(3))) float* lp =
            (__attribute__((address_space(3))) float*)&ld[0][lane & 1][0];
        lbase = (unsigned)(unsigned long long)lp;
    }

#define ISSUE(B, BUF)                                                                \
    do { const float* _p = psum + (size_t)(B) * 1048576 + (size_t)chb * 1024         \
                           + (size_t)lane * 4;                                       \
        _Pragma("unroll")                                                            \
        for (int r = 0; r < 2; ++r)                                                  \
            _Pragma("unroll")                                                        \
            for (int q = 0; q < 4; ++q)                                              \
                __builtin_amdgcn_global_load_lds(                                    \
                    (const __attribute__((address_space(1))) void*)                  \
                        (_p + r * 1024 + q * 256),                                   \
                    (__attribute__((address_space(3))) void*)                        \
                        ((__attribute__((address_space(3))) float*)                  \
                            &ld[BUF][r][q * 256]),                                   \
                    16, 0, 0);                                                       \
    } while (0)

#define WVM(N)                                                                       \
    do { __builtin_amdgcn_sched_barrier(0);                                          \
         asm volatile("s_waitcnt vmcnt(" #N ")" ::: "memory");                       \
         __builtin_amdgcn_sched_barrier(0); } while (0)

#define WLG(N)                                                                       \
    do { asm volatile("s_waitcnt lgkmcnt(" #N ")" :::);                              \
         __builtin_amdgcn_sched_barrier(0); } while (0)

#define DSR8(P0,P1,P2,P3,P4,P5,P6,P7, G, RA)                                         \
    do {                                                                             \
        asm volatile("ds_read_b128 %0, %1 offset:%c2" : "=v"(P0) : "v"(RA), "i"((G)*128 +   0)); \
        asm volatile("ds_read_b128 %0, %1 offset:%c2" : "=v"(P1) : "v"(RA), "i"((G)*128 +  16)); \
        asm volatile("ds_read_b128 %0, %1 offset:%c2" : "=v"(P2) : "v"(RA), "i"((G)*128 +  32)); \
        asm volatile("ds_read_b128 %0, %1 offset:%c2" : "=v"(P3) : "v"(RA), "i"((G)*128 +  48)); \
        asm volatile("ds_read_b128 %0, %1 offset:%c2" : "=v"(P4) : "v"(RA), "i"((G)*128 +  64)); \
        asm volatile("ds_read_b128 %0, %1 offset:%c2" : "=v"(P5) : "v"(RA), "i"((G)*128 +  80)); \
        asm volatile("ds_read_b128 %0, %1 offset:%c2" : "=v"(P6) : "v"(RA), "i"((G)*128 +  96)); \
        asm volatile("ds_read_b128 %0, %1 offset:%c2" : "=v"(P7) : "v"(RA), "i"((G)*128 + 112)); \
    } while (0)

#define SUM4(V)  do { s = s + (V).x; s = s + (V).y; s = s + (V).z; s = s + (V).w; } while (0)
#define SUM8(Q0,Q1,Q2,Q3,Q4,Q5,Q6,Q7)                                                \
    do { SUM4(Q0); SUM4(Q1); SUM4(Q2); SUM4(Q3);                                     \
         SUM4(Q4); SUM4(Q5); SUM4(Q6); SUM4(Q7); } while (0)

#define VAR4(V)                                                                      \
    do { float d0 = (V).x - mean; float q0 = d0 * d0; v = v + q0;                    \
         float d1 = (V).y - mean; float q1 = d1 * d1; v = v + q1;                    \
         float d2 = (V).z - mean; float q2 = d2 * d2; v = v + q2;                    \
         float d3 = (V).w - mean; float q3 = d3 * d3; v = v + q3; } while (0)
#define VAR8(Q0,Q1,Q2,Q3,Q4,Q5,Q6,Q7)                                                \
    do { VAR4(Q0); VAR4(Q1); VAR4(Q2); VAR4(Q3);                                     \
         VAR4(Q4); VAR4(Q5); VAR4(Q6); VAR4(Q7); } while (0)

    // ---- pass 1: mean (exact v8 element order: b-major, linear (h,w) within) ----
    ISSUE(0, 0); ISSUE(1, 1); ISSUE(2, 2);
    float s = 0.f;
#pragma unroll 1
    for (int b = 0; b < 32; ++b) {
        if (b + 3 < 32)      { ISSUE(b + 3, (b + 3) & 3); WVM(24); }
        else if (b == 29)    { WVM(16); }
        else if (b == 30)    { WVM(8);  }
        else                 { WVM(0);  }
        unsigned ra = lbase + (unsigned)((b & 3) * 8224);
        f4 A0,A1,A2,A3,A4,A5,A6,A7, B0,B1,B2,B3,B4,B5,B6,B7;
        DSR8(A0,A1,A2,A3,A4,A5,A6,A7, 0, ra);
#pragma unroll
        for (int g = 0; g < 32; g += 2) {
            DSR8(B0,B1,B2,B3,B4,B5,B6,B7, g + 1, ra);
            WLG(8);
            SUM8(A0,A1,A2,A3,A4,A5,A6,A7);
            if (g + 2 < 32) { DSR8(A0,A1,A2,A3,A4,A5,A6,A7, g + 2, ra); WLG(8); }
            else            { WLG(0); }
            SUM8(B0,B1,B2,B3,B4,B5,B6,B7);
        }
    }
    float mean = s / 32768.0f;

    // ---- pass 2: var — d=p-mean; q=d*d; v=v+q in exact element order ----
    ISSUE(0, 0); ISSUE(1, 1); ISSUE(2, 2);
    float v = 0.f;
#pragma unroll 1
    for (int b = 0; b < 32; ++b) {
        if (b + 3 < 32)      { ISSUE(b + 3, (b + 3) & 3); WVM(24); }
        else if (b == 29)    { WVM(16); }
        else if (b == 30)    { WVM(8);  }
        else                 { WVM(0);  }
        unsigned ra = lbase + (unsigned)((b & 3) * 8224);
        f4 A0,A1,A2,A3,A4,A5,A6,A7, B0,B1,B2,B3,B4,B5,B6,B7;
        DSR8(A0,A1,A2,A3,A4,A5,A6,A7, 0, ra);
#pragma unroll
        for (int g = 0; g < 32; g += 2) {
            DSR8(B0,B1,B2,B3,B4,B5,B6,B7, g + 1, ra);
            WLG(8);
            VAR8(A0,A1,A2,A3,A4,A5,A6,A7);
            if (g + 2 < 32) { DSR8(A0,A1,A2,A3,A4,A5,A6,A7, g + 2, ra); WLG(8); }
            else            { WLG(0); }
            VAR8(B0,B1,B2,B3,B4,B5,B6,B7);
        }
    }

    if (lane < 2) {
        int ch = chb + lane;
        float var = v / 32768.0f;
        float sq = sqrtf(var + 1e-5f);
        float inv = 1.0f / sq;
        inv = inv * gamma[ch];
        float mb = mean * inv;
        invA[ch] = inv;
        btA[ch] = beta[ch] - mb;
    }
#undef ISSUE
#undef WVM
#undef WLG
#undef DSR8
#undef SUM4
#undef SUM8
#undef VAR4
#undef VAR8
}

// ---------------- K3: BN apply + sign + merge + literal qrelu (unchanged, passed) ----------------
__global__ __launch_bounds__(256) void k_apply(const float* __restrict__ psum,
                                               const float* __restrict__ invA,
                                               const float* __restrict__ btA,
                                               float* __restrict__ out) {
#pragma clang fp contract(off)
    int idx = blockIdx.x * 256 + threadIdx.x;
    int w4 = (idx & 7) * 4;
    int hh = (idx >> 3) & 31;
    int co = (idx >> 8) & 255;
    int b  = idx >> 16;

    float s0 = 0.f, s1 = 0.f, s2 = 0.f, s3 = 0.f;
    for (int g = 0; g < 4; ++g) {
        int ch = g * 256 + co;
        const float4 p = *(const float4*)(psum + (((size_t)b * 1024 + ch) * 32 + hh) * 32 + w4);
        float iv = invA[ch], bt = btA[ch];
        float y0 = p.x * iv; y0 = y0 + bt;
        float y1 = p.y * iv; y1 = y1 + bt;
        float y2 = p.z * iv; y2 = y2 + bt;
        float y3 = p.w * iv; y3 = y3 + bt;
        s0 = s0 + ((y0 >= 0.f) ? 1.f : -1.f);
        s1 = s1 + ((y1 >= 0.f) ? 1.f : -1.f);
        s2 = s2 + ((y2 >= 0.f) ? 1.f : -1.f);
        s3 = s3 + ((y3 >= 0.f) ? 1.f : -1.f);
    }
    float4 q;
    {
        float u, rr, qq;
        u = s0 * 0.25f; u = fminf(fmaxf(u, 0.f), 1.f); rr = rintf(u * 15.f); qq = rr / 15.f; q.x = qq * 4.f;
        u = s1 * 0.25f; u = fminf(fmaxf(u, 0.f), 1.f); rr = rintf(u * 15.f); qq = rr / 15.f; q.y = qq * 4.f;
        u = s2 * 0.25f; u = fminf(fmaxf(u, 0.f), 1.f); rr = rintf(u * 15.f); qq = rr / 15.f; q.z = qq * 4.f;
        u = s3 * 0.25f; u = fminf(fmaxf(u, 0.f), 1.f); rr = rintf(u * 15.f); qq = rr / 15.f; q.w = qq * 4.f;
    }
    *(float4*)(out + (((size_t)b * 256 + co) * 32 + hh) * 32 + w4) = q;
}

extern "C" void kernel_launch(void* const* d_in, const int* in_sizes, int n_in,
                              void* d_out, int out_size, void* d_ws, size_t ws_size,
                              hipStream_t stream) {
    (void)in_sizes; (void)n_in; (void)out_size; (void)ws_size;
    const float* x     = (const float*)d_in[0];
    const float* w     = (const float*)d_in[1];
    const float* gamma = (const float*)d_in[2];
    const float* beta  = (const float*)d_in[3];
    float* out = (float*)d_out;
    char* ws = (char*)d_ws;
    float* psum  = (float*)(ws + OFF_PSUM);
    float* alpha = (float*)(ws + OFF_ALPHA);
    float* invA  = (float*)(ws + OFF_INV);
    float* btA   = (float*)(ws + OFF_BT);
    float* wsaT  = out;                 // 2.36 MB scratch in d_out; k_apply overwrites later

    hipLaunchKernelGGL(k_alpha, dim3(256),  dim3(256), 0, stream, w, alpha);
    hipLaunchKernelGGL(k_wsaT,  dim3(2304), dim3(256), 0, stream, w, alpha, wsaT);
    hipLaunchKernelGGL(k_conv,  dim3(512),  dim3(512), 0, stream, x, wsaT, psum);
    hipLaunchKernelGGL(k_stats, dim3(512),  dim3(64),  0, stream, psum, gamma, beta, invA, btA);
    hipLaunchKernelGGL(k_apply, dim3(8192), dim3(256), 0, stream, psum, invA, btA, out);
}

// Round 14
// 805.717 us; speedup vs baseline: 1.0631x; 1.0631x over previous
//
// v22: restore the proven 800us configuration (k_conv = v10 verbatim, stats =
// v15 structure) with ONE zero-risk change: k_stats split into k_mean + k_var
// (v15 pass bodies verbatim; mean parked in invA, re-read by k_var) so each
// pass gets its own rocprof row. Diagnostic round — localize the stats stall.
#include <hip/hip_runtime.h>

#define OFF_PSUM   0UL            // 134217728 B  f32 psum[b][1024][32][32]
#define OFF_ALPHA  134217728UL    // 1024 B
#define OFF_INV    134218752UL    // 4096 B
#define OFF_BT     134222848UL    // 4096 B   (total 134.23 MB, proven fits)

// ---------------- K0a: alpha — LDS-staged, exact sequential chain ----------------
__global__ __launch_bounds__(256) void k_alpha(const float* __restrict__ w,
                                               float* __restrict__ alpha) {
#pragma clang fp contract(off)
    __shared__ float buf[2304];
    int co = blockIdx.x, t = threadIdx.x;
    const float* p = w + (size_t)co * 2304;
    for (int i = t; i < 2304; i += 256) buf[i] = p[i];
    __syncthreads();
    if (t == 0) {
        float s = 0.f;
#pragma unroll 16
        for (int k = 0; k < 2304; ++k) s = s + fabsf(buf[k]);
        alpha[co] = s / 2304.0f;
    }
}

// ---------------- K0b: transposed +-alpha table wsaT[((g*9+tap)*64+ci)*256+co] ----------------
__global__ __launch_bounds__(256) void k_wsaT(const float* __restrict__ w,
                                              const float* __restrict__ alpha,
                                              float* __restrict__ wsaT) {
    int item = blockIdx.x * 256 + threadIdx.x;     // 589824 items
    int co = item & 255;
    int rest = item >> 8;                           // 0..2303
    int ci = rest & 63;
    int t9 = rest >> 6;                             // 0..35
    int tap = t9 % 9, g = t9 / 9;
    float av = alpha[co];
    float wv = w[((size_t)co * 256 + g * 64 + ci) * 9 + tap];
    wsaT[item] = (wv >= 0.f) ? av : -av;           // exact +-alpha
}

// ---------------- K1: conv — v10: 2 px/thread, SGPR weights, 64 FMA per weight row ----------------
__global__ __launch_bounds__(512, 4) void k_conv(const float* __restrict__ x,
                                                 const float* __restrict__ wsaT,
                                                 float* __restrict__ psum) {
#pragma clang fp contract(off)
    __shared__ float xs[6][34][68];
    int bx = blockIdx.x;
    int band = bx & 7, g = (bx >> 3) & 3, b = bx >> 5;   // 1024 blocks
    int t = threadIdx.x;

    const float* xg = x + (size_t)(b * 256 + g * 64) * 1024;
#pragma unroll 1
    for (int i = 0; i < 26; ++i) {                 // 6*34*64 = 13056 elements
        int idx = i * 512 + t;
        if (idx < 13056) {
            int ci = idx & 63, col = (idx >> 6) % 34, row = idx / 2176;
            int gr = band * 4 + row - 1, gc = col - 1;
            float v = (gr >= 0 && gr < 32 && gc >= 0 && gc < 32)
                        ? xg[(size_t)ci * 1024 + gr * 32 + gc] : 0.f;
            xs[row][col][ci] = v;
        }
    }
    __syncthreads();

    int wid = t >> 6, lane = t & 63;
    int r = lane >> 5, m = lane & 31;
    int h0 = band * 4 + r;                          // second px at h0+2
    int cobase = __builtin_amdgcn_readfirstlane(wid * 32);   // wave-uniform

    float acc0[32], acc1[32];
#pragma unroll
    for (int j = 0; j < 32; ++j) { acc0[j] = 0.f; acc1[j] = 0.f; }

#pragma unroll 1
    for (int kh = 0; kh < 3; ++kh)
#pragma unroll 1
        for (int kw = 0; kw < 3; ++kw) {
            int tap = kh * 3 + kw;
            const float* bp0 = &xs[r + kh][m + kw][0];
            const float* bp1 = &xs[r + 2 + kh][m + kw][0];
            const float* wt = wsaT + (((size_t)(g * 9 + tap) * 64) << 8) + cobase;
#pragma unroll
            for (int c = 0; c < 4; ++c) {           // ci chunks of 16
                float xv0[16], xv1[16];
#pragma unroll
                for (int q = 0; q < 4; ++q) {
                    float4 a = *(const float4*)(bp0 + c * 16 + q * 4);
                    xv0[q * 4 + 0] = a.x; xv0[q * 4 + 1] = a.y;
                    xv0[q * 4 + 2] = a.z; xv0[q * 4 + 3] = a.w;
                    float4 d = *(const float4*)(bp1 + c * 16 + q * 4);
                    xv1[q * 4 + 0] = d.x; xv1[q * 4 + 1] = d.y;
                    xv1[q * 4 + 2] = d.z; xv1[q * 4 + 3] = d.w;
                }
#pragma unroll
                for (int ci = 0; ci < 16; ++ci) {   // per-acc chain order preserved
                    const float* wr = wt + ((c * 16 + ci) << 8);  // uniform -> s_load
#pragma unroll
                    for (int j = 0; j < 32; ++j)
                        acc0[j] = fmaf(xv0[ci], wr[j], acc0[j]);
#pragma unroll
                    for (int j = 0; j < 32; ++j)
                        acc1[j] = fmaf(xv1[ci], wr[j], acc1[j]);
                }
            }
        }

#pragma unroll
    for (int j = 0; j < 32; ++j) {
        int co = cobase + j;
        size_t rowo = ((size_t)b * 1024 + g * 256 + co) * 32;
        psum[(rowo + h0) * 32 + m]     = acc0[j];
        psum[(rowo + h0 + 2) * 32 + m] = acc1[j];
    }
}

// ---------------- shared K2 machinery (v15 verbatim) ----------------
typedef float f4 __attribute__((ext_vector_type(4)));

#define ISSUE(B, BUF)                                                                \
    do { const float* _p = psum + (size_t)(B) * 1048576 + (size_t)chb * 1024         \
                           + (size_t)lane * 4;                                       \
        _Pragma("unroll")                                                            \
        for (int r = 0; r < 2; ++r)                                                  \
            _Pragma("unroll")                                                        \
            for (int q = 0; q < 4; ++q)                                              \
                __builtin_amdgcn_global_load_lds(                                    \
                    (const __attribute__((address_space(1))) void*)                  \
                        (_p + r * 1024 + q * 256),                                   \
                    (__attribute__((address_space(3))) void*)                        \
                        ((__attribute__((address_space(3))) float*)                  \
                            &ld[BUF][r][q * 256]),                                   \
                    16, 0, 0);                                                       \
    } while (0)

#define WVM(N)                                                                       \
    do { __builtin_amdgcn_sched_barrier(0);                                          \
         asm volatile("s_waitcnt vmcnt(" #N ")" ::: "memory");                       \
         __builtin_amdgcn_sched_barrier(0); } while (0)

#define WLG(N)                                                                       \
    do { asm volatile("s_waitcnt lgkmcnt(" #N ")" :::);                              \
         __builtin_amdgcn_sched_barrier(0); } while (0)

#define DSR8(P0,P1,P2,P3,P4,P5,P6,P7, G, RA)                                         \
    do {                                                                             \
        asm volatile("ds_read_b128 %0, %1 offset:%c2" : "=v"(P0) : "v"(RA), "i"((G)*128 +   0)); \
        asm volatile("ds_read_b128 %0, %1 offset:%c2" : "=v"(P1) : "v"(RA), "i"((G)*128 +  16)); \
        asm volatile("ds_read_b128 %0, %1 offset:%c2" : "=v"(P2) : "v"(RA), "i"((G)*128 +  32)); \
        asm volatile("ds_read_b128 %0, %1 offset:%c2" : "=v"(P3) : "v"(RA), "i"((G)*128 +  48)); \
        asm volatile("ds_read_b128 %0, %1 offset:%c2" : "=v"(P4) : "v"(RA), "i"((G)*128 +  64)); \
        asm volatile("ds_read_b128 %0, %1 offset:%c2" : "=v"(P5) : "v"(RA), "i"((G)*128 +  80)); \
        asm volatile("ds_read_b128 %0, %1 offset:%c2" : "=v"(P6) : "v"(RA), "i"((G)*128 +  96)); \
        asm volatile("ds_read_b128 %0, %1 offset:%c2" : "=v"(P7) : "v"(RA), "i"((G)*128 + 112)); \
    } while (0)

#define SUM4(V)  do { s = s + (V).x; s = s + (V).y; s = s + (V).z; s = s + (V).w; } while (0)
#define SUM8(Q0,Q1,Q2,Q3,Q4,Q5,Q6,Q7)                                                \
    do { SUM4(Q0); SUM4(Q1); SUM4(Q2); SUM4(Q3);                                     \
         SUM4(Q4); SUM4(Q5); SUM4(Q6); SUM4(Q7); } while (0)

#define VAR4(V)                                                                      \
    do { float d0 = (V).x - mean; float q0 = d0 * d0; v = v + q0;                    \
         float d1 = (V).y - mean; float q1 = d1 * d1; v = v + q1;                    \
         float d2 = (V).z - mean; float q2 = d2 * d2; v = v + q2;                    \
         float d3 = (V).w - mean; float q3 = d3 * d3; v = v + q3; } while (0)
#define VAR8(Q0,Q1,Q2,Q3,Q4,Q5,Q6,Q7)                                                \
    do { VAR4(Q0); VAR4(Q1); VAR4(Q2); VAR4(Q3);                                     \
         VAR4(Q4); VAR4(Q5); VAR4(Q6); VAR4(Q7); } while (0)

// ---------------- K2a: mean pass (v15 pass-1 verbatim) — mean parked in invA ----------------
__global__ __launch_bounds__(64, 1) void k_mean(const float* __restrict__ psum,
                                                float* __restrict__ invA) {
#pragma clang fp contract(off)
    __shared__ float ld[4][2][1028];               // 32896 B; 4 bufs x 2 ch, +4 pad
    int blk = blockIdx.x, lane = threadIdx.x;
    int chb = blk * 2;

    unsigned lbase;
    {
        __attribute__((address_space(3))) float* lp =
            (__attribute__((address_space(3))) float*)&ld[0][lane & 1][0];
        lbase = (unsigned)(unsigned long long)lp;
    }

    ISSUE(0, 0); ISSUE(1, 1); ISSUE(2, 2);
    float s = 0.f;
#pragma unroll 1
    for (int b = 0; b < 32; ++b) {
        if (b + 3 < 32)      { ISSUE(b + 3, (b + 3) & 3); WVM(24); }
        else if (b == 29)    { WVM(16); }
        else if (b == 30)    { WVM(8);  }
        else                 { WVM(0);  }
        unsigned ra = lbase + (unsigned)((b & 3) * 8224);
        f4 A0,A1,A2,A3,A4,A5,A6,A7, B0,B1,B2,B3,B4,B5,B6,B7;
        DSR8(A0,A1,A2,A3,A4,A5,A6,A7, 0, ra);
#pragma unroll
        for (int g = 0; g < 32; g += 2) {
            DSR8(B0,B1,B2,B3,B4,B5,B6,B7, g + 1, ra);
            WLG(8);
            SUM8(A0,A1,A2,A3,A4,A5,A6,A7);
            if (g + 2 < 32) { DSR8(A0,A1,A2,A3,A4,A5,A6,A7, g + 2, ra); WLG(8); }
            else            { WLG(0); }
            SUM8(B0,B1,B2,B3,B4,B5,B6,B7);
        }
    }
    if (lane < 2) invA[chb + lane] = s / 32768.0f;   // park mean
}

// ---------------- K2b: var pass (v15 pass-2 verbatim) — reads parked mean ----------------
__global__ __launch_bounds__(64, 1) void k_var(const float* __restrict__ psum,
                                               const float* __restrict__ gamma,
                                               const float* __restrict__ beta,
                                               float* __restrict__ invA,
                                               float* __restrict__ btA) {
#pragma clang fp contract(off)
    __shared__ float ld[4][2][1028];
    int blk = blockIdx.x, lane = threadIdx.x;
    int chb = blk * 2;

    float mean = invA[chb + (lane & 1)];            // parked by k_mean

    unsigned lbase;
    {
        __attribute__((address_space(3))) float* lp =
            (__attribute__((address_space(3))) float*)&ld[0][lane & 1][0];
        lbase = (unsigned)(unsigned long long)lp;
    }

    ISSUE(0, 0); ISSUE(1, 1); ISSUE(2, 2);
    float v = 0.f;
#pragma unroll 1
    for (int b = 0; b < 32; ++b) {
        if (b + 3 < 32)      { ISSUE(b + 3, (b + 3) & 3); WVM(24); }
        else if (b == 29)    { WVM(16); }
        else if (b == 30)    { WVM(8);  }
        else                 { WVM(0);  }
        unsigned ra = lbase + (unsigned)((b & 3) * 8224);
        f4 A0,A1,A2,A3,A4,A5,A6,A7, B0,B1,B2,B3,B4,B5,B6,B7;
        DSR8(A0,A1,A2,A3,A4,A5,A6,A7, 0, ra);
#pragma unroll
        for (int g = 0; g < 32; g += 2) {
            DSR8(B0,B1,B2,B3,B4,B5,B6,B7, g + 1, ra);
            WLG(8);
            VAR8(A0,A1,A2,A3,A4,A5,A6,A7);
            if (g + 2 < 32) { DSR8(A0,A1,A2,A3,A4,A5,A6,A7, g + 2, ra); WLG(8); }
            else            { WLG(0); }
            VAR8(B0,B1,B2,B3,B4,B5,B6,B7);
        }
    }

    if (lane < 2) {
        int ch = chb + lane;
        float var = v / 32768.0f;
        float sq = sqrtf(var + 1e-5f);
        float inv = 1.0f / sq;
        inv = inv * gamma[ch];
        float mb = mean * inv;
        invA[ch] = inv;
        btA[ch] = beta[ch] - mb;
    }
}

// ---------------- K3: BN apply + sign + merge + literal qrelu (unchanged, passed) ----------------
__global__ __launch_bounds__(256) void k_apply(const float* __restrict__ psum,
                                               const float* __restrict__ invA,
                                               const float* __restrict__ btA,
                                               float* __restrict__ out) {
#pragma clang fp contract(off)
    int idx = blockIdx.x * 256 + threadIdx.x;
    int w4 = (idx & 7) * 4;
    int hh = (idx >> 3) & 31;
    int co = (idx >> 8) & 255;
    int b  = idx >> 16;

    float s0 = 0.f, s1 = 0.f, s2 = 0.f, s3 = 0.f;
    for (int g = 0; g < 4; ++g) {
        int ch = g * 256 + co;
        const float4 p = *(const float4*)(psum + (((size_t)b * 1024 + ch) * 32 + hh) * 32 + w4);
        float iv = invA[ch], bt = btA[ch];
        float y0 = p.x * iv; y0 = y0 + bt;
        float y1 = p.y * iv; y1 = y1 + bt;
        float y2 = p.z * iv; y2 = y2 + bt;
        float y3 = p.w * iv; y3 = y3 + bt;
        s0 = s0 + ((y0 >= 0.f) ? 1.f : -1.f);
        s1 = s1 + ((y1 >= 0.f) ? 1.f : -1.f);
        s2 = s2 + ((y2 >= 0.f) ? 1.f : -1.f);
        s3 = s3 + ((y3 >= 0.f) ? 1.f : -1.f);
    }
    float4 q;
    {
        float u, rr, qq;
        u = s0 * 0.25f; u = fminf(fmaxf(u, 0.f), 1.f); rr = rintf(u * 15.f); qq = rr / 15.f; q.x = qq * 4.f;
        u = s1 * 0.25f; u = fminf(fmaxf(u, 0.f), 1.f); rr = rintf(u * 15.f); qq = rr / 15.f; q.y = qq * 4.f;
        u = s2 * 0.25f; u = fminf(fmaxf(u, 0.f), 1.f); rr = rintf(u * 15.f); qq = rr / 15.f; q.z = qq * 4.f;
        u = s3 * 0.25f; u = fminf(fmaxf(u, 0.f), 1.f); rr = rintf(u * 15.f); qq = rr / 15.f; q.w = qq * 4.f;
    }
    *(float4*)(out + (((size_t)b * 256 + co) * 32 + hh) * 32 + w4) = q;
}

extern "C" void kernel_launch(void* const* d_in, const int* in_sizes, int n_in,
                              void* d_out, int out_size, void* d_ws, size_t ws_size,
                              hipStream_t stream) {
    (void)in_sizes; (void)n_in; (void)out_size; (void)ws_size;
    const float* x     = (const float*)d_in[0];
    const float* w     = (const float*)d_in[1];
    const float* gamma = (const float*)d_in[2];
    const float* beta  = (const float*)d_in[3];
    float* out = (float*)d_out;
    char* ws = (char*)d_ws;
    float* psum  = (float*)(ws + OFF_PSUM);
    float* alpha = (float*)(ws + OFF_ALPHA);
    float* invA  = (float*)(ws + OFF_INV);
    float* btA   = (float*)(ws + OFF_BT);
    float* wsaT  = out;                 // 2.36 MB scratch in d_out; k_apply overwrites later

    hipLaunchKernelGGL(k_alpha, dim3(256),  dim3(256), 0, stream, w, alpha);
    hipLaunchKernelGGL(k_wsaT,  dim3(2304), dim3(256), 0, stream, w, alpha, wsaT);
    hipLaunchKernelGGL(k_conv,  dim3(1024), dim3(512), 0, stream, x, wsaT, psum);
    hipLaunchKernelGGL(k_mean,  dim3(512),  dim3(64),  0, stream, psum, invA);
    hipLaunchKernelGGL(k_var,   dim3(512),  dim3(64),  0, stream, psum, gamma, beta, invA, btA);
    hipLaunchKernelGGL(k_apply, dim3(8192), dim3(256), 0, stream, psum, invA, btA, out);
}